// Round 4
// baseline (197.278 us; speedup 1.0000x reference)
//
#include <hip/hip_runtime.h>
#include <math.h>

namespace {

constexpr int B_ = 8;
constexpr int C_ = 256;
constexpr int N_ = 4096;

constexpr int TM = 64;    // m-rows per attn block
constexpr int TN = 128;   // n-chunk per iteration
constexpr int NCH = N_ / TN;
constexpr int PSTRIDE = 136;  // ps row stride in bf16 (16B-aligned rows)
constexpr float LOG2E = 1.4426950408889634f;

// V tiled layout: v_t[b][nblk][c][nin], 16 n-values per block, stored in
// "ps order": within each 32-col group, position p holds n-value
//   n32 = (p&3) + 8*((p>>2)&3) + 4*(p>>4)
// which is exactly the r-register order of the swapped-QK MFMA C-layout.
// This lets the attn kernel write each lane's 16 P values as TWO contiguous
// ds_write_b128 (conflict-free), with the permutation absorbed here in V's
// storage order (PV contracts over n, so any shared A/B k-order is valid).
constexpr int VBLK = C_ * 16;   // elements per nblk

typedef __attribute__((ext_vector_type(8))) short short8;    // 8 bf16
typedef __attribute__((ext_vector_type(16))) float float16;  // 16 fp32 acc

__device__ inline unsigned short f2bf(float f) {
  unsigned u = __float_as_uint(f);
  u += 0x7FFFu + ((u >> 16) & 1u);   // RNE
  return (unsigned short)(u >> 16);
}
__device__ inline float bf2f(unsigned short h) {
  return __uint_as_float(((unsigned)h) << 16);
}

// Raw hardware exp2: 1-ulp, single instruction (libm exp2f lowers to the
// multi-instruction OCML sequence; was the dominant VALU consumer).
__device__ inline float fast_exp2(float x) {
  float r;
  asm("v_exp_f32 %0, %1" : "=v"(r) : "v"(x));
  return r;
}

// ---- prep: wv -> bf16 ; wqk A-matrix [wq*log2e hi(8); lo(8); wk hi(8); lo(8)] ----
__global__ __launch_bounds__(256) void prep_kernel(
    const float* __restrict__ wv, const float* __restrict__ wq,
    const float* __restrict__ wk,
    unsigned short* __restrict__ wv_bf, unsigned short* __restrict__ wqk_bf) {
  const int i = blockIdx.x * 256 + threadIdx.x;   // grid 256 -> 65536 threads
  wv_bf[i] = f2bf(wv[i]);
  if (i < 2048) {
    const int d = i >> 8, c = i & 255;
    const float qL = wq[i] * LOG2E;
    const unsigned short hq = f2bf(qL);
    wqk_bf[d * 256 + c]        = hq;
    wqk_bf[(d + 8) * 256 + c]  = f2bf(qL - bf2f(hq));
    const float kv = wk[i];
    const unsigned short hk = f2bf(kv);
    wqk_bf[(d + 16) * 256 + c] = hk;
    wqk_bf[(d + 24) * 256 + c] = f2bf(kv - bf2f(hk));
  }
}

// Build a bf16 B-fragment (8 consecutive k=c values at column n) from fp32 LDS.
// 4x v_cvt_pk_bf16_f32 (RNE, bit-identical to f2bf).
__device__ inline short8 xfrag(const float* xs, int c0, int n) {
  const float* base = xs + c0 * 32 + n;
  uint4 p;
  asm("v_cvt_pk_bf16_f32 %0, %1, %2" : "=v"(p.x) : "v"(base[0]),   "v"(base[32]));
  asm("v_cvt_pk_bf16_f32 %0, %1, %2" : "=v"(p.y) : "v"(base[64]),  "v"(base[96]));
  asm("v_cvt_pk_bf16_f32 %0, %1, %2" : "=v"(p.z) : "v"(base[128]), "v"(base[160]));
  asm("v_cvt_pk_bf16_f32 %0, %1, %2" : "=v"(p.w) : "v"(base[192]), "v"(base[224]));
  return __builtin_bit_cast(short8, p);
}

// ---- fused projection, all-MFMA, async-staged; V written in ps-order tiles ----
__global__ __launch_bounds__(256, 4) void proj_kernel(
    const float* __restrict__ x,
    const float* __restrict__ bq, const float* __restrict__ bk,
    const unsigned short* __restrict__ wqk_bf,
    const unsigned short* __restrict__ wv_bf, const float* __restrict__ bv,
    unsigned short* __restrict__ q_t, unsigned short* __restrict__ k_th,
    unsigned short* __restrict__ k_tl, unsigned short* __restrict__ v)
{
  __shared__ float xs[256 * 32];   // [c][n] fp32, 32 KB

  const int b = blockIdx.y;
  const int n0 = blockIdx.x * 32;
  const int tid = threadIdx.x;
  const int w = tid >> 6, l = tid & 63;
  const int l31 = l & 31, lh = l >> 5;

  // async stage, width=16: wave w covers c rows [64w, 64w+64), 8 rows/instr.
  {
    const int r8 = l >> 3, c4 = (l & 7) * 4;
    const float* gp = x + ((size_t)b * C_ + w * 64 + r8) * N_ + n0 + c4;
    #pragma unroll
    for (int i = 0; i < 64; i += 8) {
      __builtin_amdgcn_global_load_lds(
          (const __attribute__((address_space(1))) void*)(gp + (size_t)i * N_),
          (__attribute__((address_space(3))) void*)(xs + (w * 64 + i) * 32), 16, 0, 0);
    }
  }
  __syncthreads();   // drains vmcnt before barrier

  // q/k MFMA: wave 0 only -> D[32 d-rows][32 n]
  if (w == 0) {
    float16 sacc;
    #pragma unroll
    for (int r = 0; r < 16; ++r) sacc[r] = 0.f;
    for (int ks = 0; ks < 16; ++ks) {
      const short8 a = *reinterpret_cast<const short8*>(
          wqk_bf + l31 * 256 + ks * 16 + lh * 8);
      const short8 bfg = xfrag(xs, ks * 16 + lh * 8, l31);
      sacc = __builtin_amdgcn_mfma_f32_32x32x16_bf16(a, bfg, sacc, 0, 0, 0);
    }
    // rows: d=q_hi, d+8=q_lo, d+16=k_hi, d+24=k_lo ; lane holds d = r+4*lh, r<4
    const size_t gn = (size_t)b * N_ + n0 + l31;
    #pragma unroll
    for (int r = 0; r < 4; ++r) {
      const int d = r + 4 * lh;
      const float qv = sacc[r] + sacc[r + 4] + bq[d] * LOG2E;
      const unsigned short hq = f2bf(qv);
      q_t[gn * 16 + d]     = hq;
      q_t[gn * 16 + 8 + d] = f2bf(qv - bf2f(hq));
      const float kv = sacc[r + 8] + sacc[r + 12] + bk[d];
      const unsigned short hk = f2bf(kv);
      k_th[gn * 8 + d] = hk;
      k_tl[gn * 8 + d] = f2bf(kv - bf2f(hk));
    }
  }

  // V: wave w -> c_out [64w, 64w+64) x n [0,32): 2 accs of 32x32
  float16 acc[2];
  #pragma unroll
  for (int mi = 0; mi < 2; ++mi)
    #pragma unroll
    for (int r = 0; r < 16; ++r) acc[mi][r] = 0.f;

  for (int ks = 0; ks < 16; ++ks) {
    short8 af[2];
    #pragma unroll
    for (int mi = 0; mi < 2; ++mi)
      af[mi] = *reinterpret_cast<const short8*>(
          wv_bf + (w * 64 + mi * 32 + l31) * C_ + ks * 16 + lh * 8);
    const short8 bfg = xfrag(xs, ks * 16 + lh * 8, l31);
    #pragma unroll
    for (int mi = 0; mi < 2; ++mi)
      acc[mi] = __builtin_amdgcn_mfma_f32_32x32x16_bf16(af[mi], bfg, acc[mi], 0, 0, 0);
  }

  // write V in ps-order tiled layout. n = n0 + l31 (n0 32-aligned); its
  // storage position within the 32-group is p: n32 = (p&3)+8*((p>>2)&3)+4*(p>>4)
  // inverted: p = (n&3) | (((n>>3)&3)<<2) | (((n>>2)&1)<<4).
  const int p32 = (l31 & 3) | (((l31 >> 3) & 3) << 2) | (((l31 >> 2) & 1) << 4);
  const int P32 = n0 + p32;
  const int nblk = P32 >> 4, nin = P32 & 15;
  #pragma unroll
  for (int mi = 0; mi < 2; ++mi)
    #pragma unroll
    for (int r = 0; r < 16; ++r) {
      const int c = w * 64 + mi * 32 + (r & 3) + 8 * (r >> 2) + 4 * lh;
      v[(((size_t)b * (N_ / 16) + nblk) * C_ + c) * 16 + nin] =
          f2bf(acc[mi][r] + bv[c]);
    }
}

// ---- fused attention, barrier-pipelined, tiled-V coalesced A-frags ----
// QK is computed operand-SWAPPED: S^T = mfma(A=K, B=Q-dup); m sits in the
// lane dim, n in the r-dim. Each lane's 16 exp'd values are stored in
// REGISTER order as two contiguous ds_write_b128 (conflict-free); the
// induced n-permutation is matched by V's ps-order storage.
//
// Iteration order: QK(nc+1)+exp+ps-write runs FIRST (its serial
// mfma->exp->pack->write tail retires under the PV MFMA cluster), then
// the PV chunk under setprio(1). K-frags are prefetched 2 chunks ahead.
__global__ __launch_bounds__(512, 4) void attn_kernel(
    const unsigned short* __restrict__ q_t, const unsigned short* __restrict__ k_th,
    const unsigned short* __restrict__ k_tl, const unsigned short* __restrict__ v,
    const float* __restrict__ x, const float* __restrict__ gamma,
    float* __restrict__ out)
{
  __shared__ __align__(16) unsigned short ps[2][TM][PSTRIDE];
  __shared__ float rsp[4][TM];
  __shared__ float rsn[TM];

  const int b = blockIdx.x;           // batch -> XCD affinity
  const int m0 = blockIdx.y * TM;
  const int tid = threadIdx.x;
  const int w = tid >> 6;
  const int l = tid & 63;
  const int l31 = l & 31, lh = l >> 5;
  const int mt = w >> 2, nt = w & 3;  // S^T tile of this wave
  const int nrow = nt * 32 + l31;     // A-frag row: n within chunk
  const int mcol = 32 * mt + l31;     // C col: m within block (= ps row)

  // Q B-frags, duplicated across both k-halves (lh-independent address)
  const size_t qoff = ((size_t)b * N_ + m0 + mcol) * 16;
  const short8 qh = *reinterpret_cast<const short8*>(q_t + qoff);
  const short8 ql = *reinterpret_cast<const short8*>(q_t + qoff + 8);

  // K A-frag source: lane half lh picks the hi or lo plane
  const unsigned short* kb = (lh ? k_tl : k_th) + (size_t)b * N_ * 8;

  // per-lane base into tiled V: batch b, c = 32w+l31, half lh
  const unsigned short* vlane =
      v + ((size_t)b * (N_ / 16)) * VBLK + (size_t)(w * 32 + l31) * 16 + lh * 8;

  float16 o0, o1;
  #pragma unroll
  for (int r = 0; r < 16; ++r) { o0[r] = 0.f; o1[r] = 0.f; }
  float rsum = 0.f;

  // prologue: prefetch af(chunk0); QK+exp chunk0 -> ps[0]; prefetch kf(chunk1)
  short8 af[8];
  #pragma unroll
  for (int g = 0; g < 8; ++g)
    af[g] = *reinterpret_cast<const short8*>(vlane + (size_t)g * VBLK);
  short8 kf1 = *reinterpret_cast<const short8*>(kb + (size_t)(TN + nrow) * 8);
  {
    const short8 kf0 = *reinterpret_cast<const short8*>(kb + (size_t)nrow * 8);
    float16 s;
    #pragma unroll
    for (int r = 0; r < 16; ++r) s[r] = 0.f;
    s = __builtin_amdgcn_mfma_f32_32x32x16_bf16(kf0, qh, s, 0, 0, 0);
    s = __builtin_amdgcn_mfma_f32_32x32x16_bf16(kf0, ql, s, 0, 0, 0);
    float e[16];
    #pragma unroll
    for (int r = 0; r < 16; ++r) e[r] = fast_exp2(s[r]);
    rsum += (((e[0] + e[1]) + (e[2] + e[3])) + ((e[4] + e[5]) + (e[6] + e[7]))) +
            (((e[8] + e[9]) + (e[10] + e[11])) + ((e[12] + e[13]) + (e[14] + e[15])));
    uint4 pk0, pk1;
    asm("v_cvt_pk_bf16_f32 %0, %1, %2" : "=v"(pk0.x) : "v"(e[0]), "v"(e[1]));
    asm("v_cvt_pk_bf16_f32 %0, %1, %2" : "=v"(pk0.y) : "v"(e[2]), "v"(e[3]));
    asm("v_cvt_pk_bf16_f32 %0, %1, %2" : "=v"(pk0.z) : "v"(e[4]), "v"(e[5]));
    asm("v_cvt_pk_bf16_f32 %0, %1, %2" : "=v"(pk0.w) : "v"(e[6]), "v"(e[7]));
    asm("v_cvt_pk_bf16_f32 %0, %1, %2" : "=v"(pk1.x) : "v"(e[8]), "v"(e[9]));
    asm("v_cvt_pk_bf16_f32 %0, %1, %2" : "=v"(pk1.y) : "v"(e[10]), "v"(e[11]));
    asm("v_cvt_pk_bf16_f32 %0, %1, %2" : "=v"(pk1.z) : "v"(e[12]), "v"(e[13]));
    asm("v_cvt_pk_bf16_f32 %0, %1, %2" : "=v"(pk1.w) : "v"(e[14]), "v"(e[15]));
    unsigned short* prow = &ps[0][mcol][nt * 32 + lh * 16];
    *reinterpret_cast<uint4*>(prow) = pk0;
    *reinterpret_cast<uint4*>(prow + 8) = pk1;
  }
  __syncthreads();

  #pragma unroll 2
  for (int nc = 0; nc < NCH; ++nc) {
    const int buf = nc & 1;
    const bool more = (nc + 1) < NCH;
    const int nc1 = more ? (nc + 1) : 0;      // dummy chunk 0 when done
    const int n2 = ((nc + 2) < NCH ? (nc + 2) : 0) * TN;

    // prefetch K-frag two chunks ahead (two full iterations of slack)
    const short8 kf2 = *reinterpret_cast<const short8*>(kb + (size_t)(n2 + nrow) * 8);

    // --- swapped QK + exp of chunk nc+1 into ps[buf^1] (FIRST, so the
    // serial tail overlaps the PV cluster below; kf1 loaded 2 chunks ago) ---
    if (more) {
      float16 s;
      #pragma unroll
      for (int r = 0; r < 16; ++r) s[r] = 0.f;
      s = __builtin_amdgcn_mfma_f32_32x32x16_bf16(kf1, qh, s, 0, 0, 0);
      s = __builtin_amdgcn_mfma_f32_32x32x16_bf16(kf1, ql, s, 0, 0, 0);
      float e[16];
      #pragma unroll
      for (int r = 0; r < 16; ++r) e[r] = fast_exp2(s[r]);
      rsum += (((e[0] + e[1]) + (e[2] + e[3])) + ((e[4] + e[5]) + (e[6] + e[7]))) +
              (((e[8] + e[9]) + (e[10] + e[11])) + ((e[12] + e[13]) + (e[14] + e[15])));
      uint4 pk0, pk1;
      asm("v_cvt_pk_bf16_f32 %0, %1, %2" : "=v"(pk0.x) : "v"(e[0]), "v"(e[1]));
      asm("v_cvt_pk_bf16_f32 %0, %1, %2" : "=v"(pk0.y) : "v"(e[2]), "v"(e[3]));
      asm("v_cvt_pk_bf16_f32 %0, %1, %2" : "=v"(pk0.z) : "v"(e[4]), "v"(e[5]));
      asm("v_cvt_pk_bf16_f32 %0, %1, %2" : "=v"(pk0.w) : "v"(e[6]), "v"(e[7]));
      asm("v_cvt_pk_bf16_f32 %0, %1, %2" : "=v"(pk1.x) : "v"(e[8]), "v"(e[9]));
      asm("v_cvt_pk_bf16_f32 %0, %1, %2" : "=v"(pk1.y) : "v"(e[10]), "v"(e[11]));
      asm("v_cvt_pk_bf16_f32 %0, %1, %2" : "=v"(pk1.z) : "v"(e[12]), "v"(e[13]));
      asm("v_cvt_pk_bf16_f32 %0, %1, %2" : "=v"(pk1.w) : "v"(e[14]), "v"(e[15]));
      unsigned short* prow = &ps[buf ^ 1][mcol][nt * 32 + lh * 16];
      *reinterpret_cast<uint4*>(prow) = pk0;
      *reinterpret_cast<uint4*>(prow + 8) = pk1;
    }

    // --- PV chunk nc + af reload for chunk nc+1 (coalesced tiled-V) ---
    __builtin_amdgcn_s_setprio(1);
    #pragma unroll
    for (int ks = 0; ks < 8; ++ks) {
      const short8 p0 = *reinterpret_cast<const short8*>(&ps[buf][l31][ks * 16 + lh * 8]);
      const short8 p1 = *reinterpret_cast<const short8*>(&ps[buf][32 + l31][ks * 16 + lh * 8]);
      o0 = __builtin_amdgcn_mfma_f32_32x32x16_bf16(af[ks], p0, o0, 0, 0, 0);
      o1 = __builtin_amdgcn_mfma_f32_32x32x16_bf16(af[ks], p1, o1, 0, 0, 0);
      af[ks] = *reinterpret_cast<const short8*>(vlane + (size_t)(nc1 * 8 + ks) * VBLK);
    }
    __builtin_amdgcn_s_setprio(0);

    kf1 = kf2;
    __syncthreads();
  }

  // --- row sums: lane holds sum over its 16 n-offsets x all chunks.
  // Combine lh halves, then the 4 nt-waves via LDS.
  rsum += __shfl_xor(rsum, 32);
  if (l < 32) rsp[nt][mcol] = rsum;
  __syncthreads();
  if (tid < TM) rsn[tid] = rsp[0][tid] + rsp[1][tid] + rsp[2][tid] + rsp[3][tid];
  __syncthreads();

  // --- epilogue: out = gamma/rowsum * O + x ---
  const float g = gamma[0];
  const float t0 = g / rsn[l31];
  const float t1 = g / rsn[32 + l31];
  #pragma unroll
  for (int r = 0; r < 16; ++r) {
    const int c = 32 * w + (r & 3) + 8 * (r >> 2) + 4 * lh;
    const size_t i0 = ((size_t)b * C_ + c) * N_ + m0 + l31;
    out[i0]      = fmaf(o0[r], t0, x[i0]);
    out[i0 + 32] = fmaf(o1[r], t1, x[i0 + 32]);
  }
}

}  // namespace

extern "C" void kernel_launch(void* const* d_in, const int* in_sizes, int n_in,
                              void* d_out, int out_size, void* d_ws, size_t ws_size,
                              hipStream_t stream) {
  const float* x     = (const float*)d_in[0];
  const float* wq    = (const float*)d_in[1];
  const float* bq    = (const float*)d_in[2];
  const float* wk    = (const float*)d_in[3];
  const float* bk    = (const float*)d_in[4];
  const float* wv    = (const float*)d_in[5];
  const float* bv    = (const float*)d_in[6];
  const float* gamma = (const float*)d_in[7];
  float* out = (float*)d_out;

  // ws: q_t 1MB | k_th .5MB | k_tl .5MB | wv_bf 128KB | wqk_bf 16KB | v 16MB
  char* p = (char*)d_ws;
  unsigned short* q_t    = (unsigned short*)p;  p += (size_t)B_ * N_ * 16 * 2;
  unsigned short* k_th   = (unsigned short*)p;  p += (size_t)B_ * N_ * 8 * 2;
  unsigned short* k_tl   = (unsigned short*)p;  p += (size_t)B_ * N_ * 8 * 2;
  unsigned short* wv_bf  = (unsigned short*)p;  p += (size_t)C_ * C_ * 2;
  unsigned short* wqk_bf = (unsigned short*)p;  p += (size_t)32 * C_ * 2;
  unsigned short* v      = (unsigned short*)p;

  prep_kernel<<<dim3(C_ * C_ / 256), 256, 0, stream>>>(wv, wq, wk, wv_bf, wqk_bf);
  proj_kernel<<<dim3(N_ / 32, B_), 256, 0, stream>>>(x, bq, bk, wqk_bf, wv_bf, bv,
                                                     q_t, k_th, k_tl, v);
  attn_kernel<<<dim3(B_, N_ / TM), 512, 0, stream>>>(q_t, k_th, k_tl, v, x, gamma, out);
}

// Round 5
// 191.983 us; speedup vs baseline: 1.0276x; 1.0276x over previous
//
#include <hip/hip_runtime.h>
#include <math.h>

namespace {

constexpr int B_ = 8;
constexpr int C_ = 256;
constexpr int N_ = 4096;

constexpr int TM = 64;    // m-rows per attn block
constexpr int TN = 128;   // n-chunk per iteration
constexpr int NCH = N_ / TN;
constexpr int PSTRIDE = 136;  // ps row stride in bf16 (16B-aligned rows)
constexpr float LOG2E = 1.4426950408889634f;

// V tiled layout: v_t[b][nblk][c][nin], 16 n-values per block, stored in
// "ps order": within each 32-col group, position p holds n-value
//   n32 = (p&3) + 8*((p>>2)&3) + 4*(p>>4)
// which is exactly the r-register order of the swapped-QK MFMA C-layout.
// This lets the attn kernel write each lane's 16 P values as TWO contiguous
// ds_write_b128 (conflict-free), with the permutation absorbed here in V's
// storage order (PV contracts over n, so any shared A/B k-order is valid).
constexpr int VBLK = C_ * 16;   // elements per nblk

typedef __attribute__((ext_vector_type(8))) short short8;    // 8 bf16
typedef __attribute__((ext_vector_type(16))) float float16;  // 16 fp32 acc

__device__ inline unsigned short f2bf(float f) {
  unsigned u = __float_as_uint(f);
  u += 0x7FFFu + ((u >> 16) & 1u);   // RNE
  return (unsigned short)(u >> 16);
}
__device__ inline float bf2f(unsigned short h) {
  return __uint_as_float(((unsigned)h) << 16);
}

// Raw hardware exp2: 1-ulp, single instruction (libm exp2f lowers to the
// multi-instruction OCML sequence; was the dominant VALU consumer).
__device__ inline float fast_exp2(float x) {
  float r;
  asm("v_exp_f32 %0, %1" : "=v"(r) : "v"(x));
  return r;
}

// ---- prep: wv -> bf16 ; wqk A-matrix [wq*log2e hi(8); lo(8); wk hi(8); lo(8)] ----
__global__ __launch_bounds__(256) void prep_kernel(
    const float* __restrict__ wv, const float* __restrict__ wq,
    const float* __restrict__ wk,
    unsigned short* __restrict__ wv_bf, unsigned short* __restrict__ wqk_bf) {
  const int i = blockIdx.x * 256 + threadIdx.x;   // grid 256 -> 65536 threads
  wv_bf[i] = f2bf(wv[i]);
  if (i < 2048) {
    const int d = i >> 8, c = i & 255;
    const float qL = wq[i] * LOG2E;
    const unsigned short hq = f2bf(qL);
    wqk_bf[d * 256 + c]        = hq;
    wqk_bf[(d + 8) * 256 + c]  = f2bf(qL - bf2f(hq));
    const float kv = wk[i];
    const unsigned short hk = f2bf(kv);
    wqk_bf[(d + 16) * 256 + c] = hk;
    wqk_bf[(d + 24) * 256 + c] = f2bf(kv - bf2f(hk));
  }
}

// Build a bf16 B-fragment (8 consecutive k=c values at column n) from fp32 LDS.
// 4x v_cvt_pk_bf16_f32 (RNE, bit-identical to f2bf).
__device__ inline short8 xfrag(const float* xs, int c0, int n) {
  const float* base = xs + c0 * 32 + n;
  uint4 p;
  asm("v_cvt_pk_bf16_f32 %0, %1, %2" : "=v"(p.x) : "v"(base[0]),   "v"(base[32]));
  asm("v_cvt_pk_bf16_f32 %0, %1, %2" : "=v"(p.y) : "v"(base[64]),  "v"(base[96]));
  asm("v_cvt_pk_bf16_f32 %0, %1, %2" : "=v"(p.z) : "v"(base[128]), "v"(base[160]));
  asm("v_cvt_pk_bf16_f32 %0, %1, %2" : "=v"(p.w) : "v"(base[192]), "v"(base[224]));
  return __builtin_bit_cast(short8, p);
}

// ---- fused projection, all-MFMA, async-staged; V written in ps-order tiles ----
__global__ __launch_bounds__(256, 4) void proj_kernel(
    const float* __restrict__ x,
    const float* __restrict__ bq, const float* __restrict__ bk,
    const unsigned short* __restrict__ wqk_bf,
    const unsigned short* __restrict__ wv_bf, const float* __restrict__ bv,
    unsigned short* __restrict__ q_t, unsigned short* __restrict__ k_th,
    unsigned short* __restrict__ k_tl, unsigned short* __restrict__ v)
{
  __shared__ float xs[256 * 32];   // [c][n] fp32, 32 KB

  const int b = blockIdx.y;
  const int n0 = blockIdx.x * 32;
  const int tid = threadIdx.x;
  const int w = tid >> 6, l = tid & 63;
  const int l31 = l & 31, lh = l >> 5;

  // async stage, width=16: wave w covers c rows [64w, 64w+64), 8 rows/instr.
  {
    const int r8 = l >> 3, c4 = (l & 7) * 4;
    const float* gp = x + ((size_t)b * C_ + w * 64 + r8) * N_ + n0 + c4;
    #pragma unroll
    for (int i = 0; i < 64; i += 8) {
      __builtin_amdgcn_global_load_lds(
          (const __attribute__((address_space(1))) void*)(gp + (size_t)i * N_),
          (__attribute__((address_space(3))) void*)(xs + (w * 64 + i) * 32), 16, 0, 0);
    }
  }
  __syncthreads();   // drains vmcnt before barrier

  // q/k MFMA: wave 0 only -> D[32 d-rows][32 n]
  if (w == 0) {
    float16 sacc;
    #pragma unroll
    for (int r = 0; r < 16; ++r) sacc[r] = 0.f;
    for (int ks = 0; ks < 16; ++ks) {
      const short8 a = *reinterpret_cast<const short8*>(
          wqk_bf + l31 * 256 + ks * 16 + lh * 8);
      const short8 bfg = xfrag(xs, ks * 16 + lh * 8, l31);
      sacc = __builtin_amdgcn_mfma_f32_32x32x16_bf16(a, bfg, sacc, 0, 0, 0);
    }
    // rows: d=q_hi, d+8=q_lo, d+16=k_hi, d+24=k_lo ; lane holds d = r+4*lh, r<4
    const size_t gn = (size_t)b * N_ + n0 + l31;
    #pragma unroll
    for (int r = 0; r < 4; ++r) {
      const int d = r + 4 * lh;
      const float qv = sacc[r] + sacc[r + 4] + bq[d] * LOG2E;
      const unsigned short hq = f2bf(qv);
      q_t[gn * 16 + d]     = hq;
      q_t[gn * 16 + 8 + d] = f2bf(qv - bf2f(hq));
      const float kv = sacc[r + 8] + sacc[r + 12] + bk[d];
      const unsigned short hk = f2bf(kv);
      k_th[gn * 8 + d] = hk;
      k_tl[gn * 8 + d] = f2bf(kv - bf2f(hk));
    }
  }

  // V: wave w -> c_out [64w, 64w+64) x n [0,32): 2 accs of 32x32
  float16 acc[2];
  #pragma unroll
  for (int mi = 0; mi < 2; ++mi)
    #pragma unroll
    for (int r = 0; r < 16; ++r) acc[mi][r] = 0.f;

  for (int ks = 0; ks < 16; ++ks) {
    short8 af[2];
    #pragma unroll
    for (int mi = 0; mi < 2; ++mi)
      af[mi] = *reinterpret_cast<const short8*>(
          wv_bf + (w * 64 + mi * 32 + l31) * C_ + ks * 16 + lh * 8);
    const short8 bfg = xfrag(xs, ks * 16 + lh * 8, l31);
    #pragma unroll
    for (int mi = 0; mi < 2; ++mi)
      acc[mi] = __builtin_amdgcn_mfma_f32_32x32x16_bf16(af[mi], bfg, acc[mi], 0, 0, 0);
  }

  // write V in ps-order tiled layout. n = n0 + l31 (n0 32-aligned); its
  // storage position within the 32-group is p: n32 = (p&3)+8*((p>>2)&3)+4*(p>>4)
  // inverted: p = (n&3) | (((n>>3)&3)<<2) | (((n>>2)&1)<<4).
  const int p32 = (l31 & 3) | (((l31 >> 3) & 3) << 2) | (((l31 >> 2) & 1) << 4);
  const int P32 = n0 + p32;
  const int nblk = P32 >> 4, nin = P32 & 15;
  #pragma unroll
  for (int mi = 0; mi < 2; ++mi)
    #pragma unroll
    for (int r = 0; r < 16; ++r) {
      const int c = w * 64 + mi * 32 + (r & 3) + 8 * (r >> 2) + 4 * lh;
      v[(((size_t)b * (N_ / 16) + nblk) * C_ + c) * 16 + nin] =
          f2bf(acc[mi][r] + bv[c]);
    }
}

// ---- fused attention, 4 waves, 2c x 2m accumulators per wave ----
// QK is operand-SWAPPED: S^T = mfma(A=K, B=Q-dup); m in the lane dim, n in
// the r-dim; P stored in register order (2x ds_write_b128, conflict-free),
// n-permutation absorbed by V's ps-order tiling.
// PV: each wave owns c-tiles {2w, 2w+1} x m-tiles {0,1} = 4 accumulators.
// One p0/p1 LDS read pair feeds FOUR MFMAs (was 1:1) -> per-CU LDS traffic
// -44%, below the matrix-pipe budget. V/K global traffic unchanged
// (c-tiles still loaded once per block; m-reuse is intra-wave).
__global__ __launch_bounds__(256, 2) void attn_kernel(
    const unsigned short* __restrict__ q_t, const unsigned short* __restrict__ k_th,
    const unsigned short* __restrict__ k_tl, const unsigned short* __restrict__ v,
    const float* __restrict__ x, const float* __restrict__ gamma,
    float* __restrict__ out)
{
  __shared__ __align__(16) unsigned short ps[2][TM][PSTRIDE];
  __shared__ float rsp[4][TM];
  __shared__ float rsn[TM];

  const int b = blockIdx.x;           // batch -> XCD affinity
  const int m0 = blockIdx.y * TM;
  const int tid = threadIdx.x;
  const int w = tid >> 6;             // 0..3: QK nt quarter == PV c-pair
  const int l = tid & 63;
  const int l31 = l & 31, lh = l >> 5;
  const int nrow = w * 32 + l31;      // QK A-frag row: n within chunk

  // Q B-frags for both m-tiles, duplicated across k-halves (lh-independent)
  const size_t qoff0 = ((size_t)b * N_ + m0 + l31) * 16;
  const short8 qh0 = *reinterpret_cast<const short8*>(q_t + qoff0);
  const short8 ql0 = *reinterpret_cast<const short8*>(q_t + qoff0 + 8);
  const short8 qh1 = *reinterpret_cast<const short8*>(q_t + qoff0 + 512);  // +32 rows
  const short8 ql1 = *reinterpret_cast<const short8*>(q_t + qoff0 + 520);

  // K A-frag source: lane half lh picks the hi or lo plane
  const unsigned short* kb = (lh ? k_tl : k_th) + (size_t)b * N_ * 8;

  // per-lane base into tiled V for c-tiles 2w and 2w+1
  const unsigned short* vlane0 =
      v + ((size_t)b * (N_ / 16)) * VBLK + (size_t)(2 * w * 32 + l31) * 16 + lh * 8;
  const unsigned short* vlane1 = vlane0 + 512;   // +32 c rows

  float16 o00, o01, o10, o11;   // [c-tile][m-tile]
  #pragma unroll
  for (int r = 0; r < 16; ++r) { o00[r] = 0.f; o01[r] = 0.f; o10[r] = 0.f; o11[r] = 0.f; }
  float rsum0 = 0.f, rsum1 = 0.f;

  // QK one 32x32 tile: mfma pair -> exp -> rsum tree -> pack -> 2x b128 store
  auto qk_tile = [&](const short8& kf, const short8& qh, const short8& ql,
                     float& rs, unsigned short* prow) {
    float16 s;
    #pragma unroll
    for (int r = 0; r < 16; ++r) s[r] = 0.f;
    s = __builtin_amdgcn_mfma_f32_32x32x16_bf16(kf, qh, s, 0, 0, 0);
    s = __builtin_amdgcn_mfma_f32_32x32x16_bf16(kf, ql, s, 0, 0, 0);
    float e[16];
    #pragma unroll
    for (int r = 0; r < 16; ++r) e[r] = fast_exp2(s[r]);
    rs += (((e[0] + e[1]) + (e[2] + e[3])) + ((e[4] + e[5]) + (e[6] + e[7]))) +
          (((e[8] + e[9]) + (e[10] + e[11])) + ((e[12] + e[13]) + (e[14] + e[15])));
    uint4 pk0, pk1;
    asm("v_cvt_pk_bf16_f32 %0, %1, %2" : "=v"(pk0.x) : "v"(e[0]), "v"(e[1]));
    asm("v_cvt_pk_bf16_f32 %0, %1, %2" : "=v"(pk0.y) : "v"(e[2]), "v"(e[3]));
    asm("v_cvt_pk_bf16_f32 %0, %1, %2" : "=v"(pk0.z) : "v"(e[4]), "v"(e[5]));
    asm("v_cvt_pk_bf16_f32 %0, %1, %2" : "=v"(pk0.w) : "v"(e[6]), "v"(e[7]));
    asm("v_cvt_pk_bf16_f32 %0, %1, %2" : "=v"(pk1.x) : "v"(e[8]), "v"(e[9]));
    asm("v_cvt_pk_bf16_f32 %0, %1, %2" : "=v"(pk1.y) : "v"(e[10]), "v"(e[11]));
    asm("v_cvt_pk_bf16_f32 %0, %1, %2" : "=v"(pk1.z) : "v"(e[12]), "v"(e[13]));
    asm("v_cvt_pk_bf16_f32 %0, %1, %2" : "=v"(pk1.w) : "v"(e[14]), "v"(e[15]));
    *reinterpret_cast<uint4*>(prow) = pk0;
    *reinterpret_cast<uint4*>(prow + 8) = pk1;
  };

  // prologue: prefetch af(chunk0); QK+exp chunk0 (both m-tiles) -> ps[0];
  // prefetch kf(chunk1)
  short8 af0[8], af1[8];
  #pragma unroll
  for (int g = 0; g < 8; ++g) {
    af0[g] = *reinterpret_cast<const short8*>(vlane0 + (size_t)g * VBLK);
    af1[g] = *reinterpret_cast<const short8*>(vlane1 + (size_t)g * VBLK);
  }
  short8 kf1 = *reinterpret_cast<const short8*>(kb + (size_t)(TN + nrow) * 8);
  {
    const short8 kf0 = *reinterpret_cast<const short8*>(kb + (size_t)nrow * 8);
    qk_tile(kf0, qh0, ql0, rsum0, &ps[0][l31][w * 32 + lh * 16]);
    qk_tile(kf0, qh1, ql1, rsum1, &ps[0][32 + l31][w * 32 + lh * 16]);
  }
  __syncthreads();

  for (int nc = 0; nc < NCH; ++nc) {
    const int buf = nc & 1;
    const bool more = (nc + 1) < NCH;
    const int nc1 = more ? (nc + 1) : 0;      // dummy chunk 0 when done
    const int n2 = ((nc + 2) < NCH ? (nc + 2) : 0) * TN;

    // prefetch K-frag two chunks ahead (two full iterations of slack)
    const short8 kf2 = *reinterpret_cast<const short8*>(kb + (size_t)(n2 + nrow) * 8);

    // --- swapped QK + exp of chunk nc+1 into ps[buf^1] (FIRST, so the
    // serial tail overlaps the PV cluster below; kf1 loaded 2 chunks ago) ---
    if (more) {
      qk_tile(kf1, qh0, ql0, rsum0, &ps[buf ^ 1][l31][w * 32 + lh * 16]);
      qk_tile(kf1, qh1, ql1, rsum1, &ps[buf ^ 1][32 + l31][w * 32 + lh * 16]);
    }

    // --- PV chunk nc: one p0/p1 pair feeds 4 MFMAs; af reload for nc+1 ---
    __builtin_amdgcn_s_setprio(1);
    #pragma unroll
    for (int ks = 0; ks < 8; ++ks) {
      const short8 p0 = *reinterpret_cast<const short8*>(&ps[buf][l31][ks * 16 + lh * 8]);
      const short8 p1 = *reinterpret_cast<const short8*>(&ps[buf][32 + l31][ks * 16 + lh * 8]);
      o00 = __builtin_amdgcn_mfma_f32_32x32x16_bf16(af0[ks], p0, o00, 0, 0, 0);
      o01 = __builtin_amdgcn_mfma_f32_32x32x16_bf16(af0[ks], p1, o01, 0, 0, 0);
      o10 = __builtin_amdgcn_mfma_f32_32x32x16_bf16(af1[ks], p0, o10, 0, 0, 0);
      o11 = __builtin_amdgcn_mfma_f32_32x32x16_bf16(af1[ks], p1, o11, 0, 0, 0);
      af0[ks] = *reinterpret_cast<const short8*>(vlane0 + (size_t)(nc1 * 8 + ks) * VBLK);
      af1[ks] = *reinterpret_cast<const short8*>(vlane1 + (size_t)(nc1 * 8 + ks) * VBLK);
    }
    __builtin_amdgcn_s_setprio(0);

    kf1 = kf2;
    __syncthreads();
  }

  // --- row sums: lane holds per-m-row partials over its 16 n-offsets x chunks.
  // Combine lh halves, then the 4 nt-waves via LDS.
  rsum0 += __shfl_xor(rsum0, 32);
  rsum1 += __shfl_xor(rsum1, 32);
  if (l < 32) { rsp[w][l31] = rsum0; rsp[w][32 + l31] = rsum1; }
  __syncthreads();
  if (tid < TM) rsn[tid] = rsp[0][tid] + rsp[1][tid] + rsp[2][tid] + rsp[3][tid];
  __syncthreads();

  // --- epilogue: out = gamma/rowsum * O + x ---
  const float g = gamma[0];
  const float t0 = g / rsn[l31];
  const float t1 = g / rsn[32 + l31];
  #pragma unroll
  for (int r = 0; r < 16; ++r) {
    const int crow = (r & 3) + 8 * (r >> 2) + 4 * lh;
    const int c0 = 2 * w * 32 + crow;
    const size_t i00 = ((size_t)b * C_ + c0) * N_ + m0 + l31;
    const size_t i10 = i00 + (size_t)32 * N_;   // c-tile 2w+1
    out[i00]      = fmaf(o00[r], t0, x[i00]);
    out[i00 + 32] = fmaf(o01[r], t1, x[i00 + 32]);
    out[i10]      = fmaf(o10[r], t0, x[i10]);
    out[i10 + 32] = fmaf(o11[r], t1, x[i10 + 32]);
  }
}

}  // namespace

extern "C" void kernel_launch(void* const* d_in, const int* in_sizes, int n_in,
                              void* d_out, int out_size, void* d_ws, size_t ws_size,
                              hipStream_t stream) {
  const float* x     = (const float*)d_in[0];
  const float* wq    = (const float*)d_in[1];
  const float* bq    = (const float*)d_in[2];
  const float* wk    = (const float*)d_in[3];
  const float* bk    = (const float*)d_in[4];
  const float* wv    = (const float*)d_in[5];
  const float* bv    = (const float*)d_in[6];
  const float* gamma = (const float*)d_in[7];
  float* out = (float*)d_out;

  // ws: q_t 1MB | k_th .5MB | k_tl .5MB | wv_bf 128KB | wqk_bf 16KB | v 16MB
  char* p = (char*)d_ws;
  unsigned short* q_t    = (unsigned short*)p;  p += (size_t)B_ * N_ * 16 * 2;
  unsigned short* k_th   = (unsigned short*)p;  p += (size_t)B_ * N_ * 8 * 2;
  unsigned short* k_tl   = (unsigned short*)p;  p += (size_t)B_ * N_ * 8 * 2;
  unsigned short* wv_bf  = (unsigned short*)p;  p += (size_t)C_ * C_ * 2;
  unsigned short* wqk_bf = (unsigned short*)p;  p += (size_t)32 * C_ * 2;
  unsigned short* v      = (unsigned short*)p;

  prep_kernel<<<dim3(C_ * C_ / 256), 256, 0, stream>>>(wv, wq, wk, wv_bf, wqk_bf);
  proj_kernel<<<dim3(N_ / 32, B_), 256, 0, stream>>>(x, bq, bk, wqk_bf, wv_bf, bv,
                                                     q_t, k_th, k_tl, v);
  attn_kernel<<<dim3(B_, N_ / TM), 256, 0, stream>>>(q_t, k_th, k_tl, v, x, gamma, out);
}